// Round 2
// baseline (228.629 us; speedup 1.0000x reference)
//
#include <hip/hip_runtime.h>

#define NSTEPS 20
#define ALPHA  0.9f
#define VTH    1.0f
#define GSOMA  0.3f
#define ISCALE 0.5f

#define NOR  21
#define NORN 42
#define NLN  56
#define NPN  42
#define NKC  2000
#define NOD  34

#define TPB  256
#define KPER 8   // KCs per consumer thread: 250 * 8 = 2000

// ============ Phase 1 (fused): ORN + LN + PN dynamics -> PN spike masks ============
// One wave handles TWO batch rows. The 140 weight registers (wOl[42]+wOp[42]+wLp[56])
// are shared between both rows; per-row state is only {drive, v_orn, v_ln, v_pn}.
// Two independent row-streams per wave double ILP to hide the strict-FP serial
// accumulate chains. All accumulations keep the exact ascending-index order that
// phase1a/phase1b proved bit-exact (absmax 0.0).
__global__ __launch_bounds__(64)
void phase1_fused(const float* __restrict__ or_input,   // [B,21]
                  const float* __restrict__ or_gains,   // [21]
                  const float* __restrict__ mapping,    // [21,42]
                  const float* __restrict__ orn_to_ln,  // [42,56]
                  const float* __restrict__ orn_to_pn,  // [42,42]
                  const float* __restrict__ ln_to_pn,   // [56,42]
                  unsigned long long* __restrict__ gPN, // [B,20]
                  int batch)
{
    const int lane = threadIdx.x;
    const int rowA = blockIdx.x * 2;
    if (rowA >= batch) return;
    const int rowB = rowA + 1;
    const bool hasB = rowB < batch;

    const int jl = lane < NLN ? lane : 0;
    const int jp = lane < NPN ? lane : 0;

    float wOl[NORN], wOp[NORN], wLp[NLN];
#pragma unroll
    for (int o = 0; o < NORN; ++o) wOl[o] = orn_to_ln[o * NLN + jl];
#pragma unroll
    for (int o = 0; o < NORN; ++o) wOp[o] = orn_to_pn[o * NPN + jp];
#pragma unroll
    for (int l = 0; l < NLN; ++l) wLp[l] = ln_to_pn[l * NPN + jp];

    float spg = 0.f;
    if (lane < NOR) spg = log1pf(expf(or_gains[lane]));  // softplus

    float driveA = 0.f, driveB = 0.f;
    {
        const float* xA = or_input + (long)rowA * NOR;
        const float* xB = or_input + (long)(hasB ? rowB : rowA) * NOR;
        const int jo = lane < NORN ? lane : 0;
#pragma unroll
        for (int i = 0; i < NOR; ++i) {
            float g = __shfl(spg, i);
            float m = mapping[i * NORN + jo];
            driveA += xA[i] * g * m;
            driveB += xB[i] * g * m;
        }
        driveA *= ISCALE;
        driveB *= ISCALE;
    }

    float voA = 0.f, voB = 0.f, vlA = 0.f, vlB = 0.f, vpA = 0.f, vpB = 0.f;
    unsigned long long* outA = gPN + (long)rowA * NSTEPS;
    unsigned long long* outB = gPN + (long)rowB * NSTEPS;

    for (int t = 0; t < NSTEPS; ++t) {
        // ---- ORN LIF (lane = ORN index), both rows ----
        bool soA = false, soB = false;
        if (lane < NORN) {
            voA = ALPHA * voA + driveA;
            soA = (voA - VTH) > 0.f;
            if (soA) voA = 0.f;
            voB = ALPHA * voB + driveB;
            soB = (voB - VTH) > 0.f;
            if (soB) voB = 0.f;
        }
        const unsigned long long mOA = __ballot(soA);
        const unsigned long long mOB = __ballot(soB);
        const unsigned int aol = (unsigned int)mOA, aoh = (unsigned int)(mOA >> 32);
        const unsigned int bol = (unsigned int)mOB, boh = (unsigned int)(mOB >> 32);

        // ---- LN input: dense ascending-o (exact, s in {0,1}) ----
        float alnA = 0.f, alnB = 0.f;
#pragma unroll
        for (int o = 0; o < 32; ++o) {
            alnA += (float)((aol >> o) & 1u) * wOl[o];
            alnB += (float)((bol >> o) & 1u) * wOl[o];
        }
#pragma unroll
        for (int o = 32; o < NORN; ++o) {
            alnA += (float)((aoh >> (o - 32)) & 1u) * wOl[o];
            alnB += (float)((boh >> (o - 32)) & 1u) * wOl[o];
        }
        bool slA = false, slB = false;
        if (lane < NLN) {
            vlA = ALPHA * vlA + alnA;
            slA = (vlA - VTH) > 0.f;
            if (slA) vlA = 0.f;
            vlB = ALPHA * vlB + alnB;
            slB = (vlB - VTH) > 0.f;
            if (slB) vlB = 0.f;
        }
        const unsigned long long mLA = __ballot(slA);
        const unsigned long long mLB = __ballot(slB);
        const unsigned int all_ = (unsigned int)mLA, alh = (unsigned int)(mLA >> 32);
        const unsigned int bll = (unsigned int)mLB, blh = (unsigned int)(mLB >> 32);

        // ---- PN excitation: dense ascending-o ----
        float apnA = 0.f, apnB = 0.f;
#pragma unroll
        for (int o = 0; o < 32; ++o) {
            apnA += (float)((aol >> o) & 1u) * wOp[o];
            apnB += (float)((bol >> o) & 1u) * wOp[o];
        }
#pragma unroll
        for (int o = 32; o < NORN; ++o) {
            apnA += (float)((aoh >> (o - 32)) & 1u) * wOp[o];
            apnB += (float)((boh >> (o - 32)) & 1u) * wOp[o];
        }
        // ---- PN inhibition: dense ascending-l ----
        float hA = 0.f, hB = 0.f;
#pragma unroll
        for (int l = 0; l < 32; ++l) {
            hA += (float)((all_ >> l) & 1u) * wLp[l];
            hB += (float)((bll >> l) & 1u) * wLp[l];
        }
#pragma unroll
        for (int l = 32; l < NLN; ++l) {
            hA += (float)((alh >> (l - 32)) & 1u) * wLp[l];
            hB += (float)((blh >> (l - 32)) & 1u) * wLp[l];
        }

        bool spA = false, spB = false;
        if (lane < NPN) {
            vpA = ALPHA * vpA + apnA - hA;
            spA = (vpA - VTH) > 0.f;
            if (spA) vpA = 0.f;
            vpB = ALPHA * vpB + apnB - hB;
            spB = (vpB - VTH) > 0.f;
            if (spB) vpB = 0.f;
        }
        const unsigned long long mPA = __ballot(spA);
        const unsigned long long mPB = __ballot(spB);
        if (lane == 0) outA[t] = mPA;
        if (lane == 1 && hasB) outB[t] = mPB;
    }
}

// ===================== Phase 2: KC two-compartment + APL + logits =====================
// (R5/R9/R13-proven 93-95 us / absmax 0.0 — unchanged)
__global__ __launch_bounds__(TPB)
void phase2_kernel(const unsigned long long* __restrict__ g_masks, // [B,20]
                   const float* __restrict__ pn_to_kc,  // [42,2000]
                   const float* __restrict__ kc_to_apl, // [2000,1]
                   const float* __restrict__ apl_to_kc, // [1,2000]
                   const float* __restrict__ dec_w,     // [2000,34]
                   const float* __restrict__ dec_b,     // [34]
                   float* __restrict__ out)             // [B,34]
{
    __shared__ float sRed[2][4];
    __shared__ float sRed2[4 * NOD];

    const int tid  = threadIdx.x;
    const int lane = tid & 63;
    const int wid  = tid >> 6;
    const int b    = blockIdx.x;

    const int  kbase = tid * KPER;
    const bool act   = (kbase < NKC);   // tid < 250
    float vd[KPER], va[KPER], cnt[KPER], wa2k[KPER], wk2a[KPER];
#pragma unroll
    for (int j = 0; j < KPER; ++j) { vd[j] = 0.f; va[j] = 0.f; cnt[j] = 0.f; }
    {
        const float4* a4 = (const float4*)(apl_to_kc + (act ? kbase : 0));
        const float4* k4 = (const float4*)(kc_to_apl + (act ? kbase : 0));
        float4 a0 = a4[0], a1 = a4[1], k0 = k4[0], k1 = k4[1];
        const float g = act ? 1.f : 0.f;
        wa2k[0] = g * a0.x; wa2k[1] = g * a0.y; wa2k[2] = g * a0.z; wa2k[3] = g * a0.w;
        wa2k[4] = g * a1.x; wa2k[5] = g * a1.y; wa2k[6] = g * a1.z; wa2k[7] = g * a1.w;
        wk2a[0] = g * k0.x; wk2a[1] = g * k0.y; wk2a[2] = g * k0.z; wk2a[3] = g * k0.w;
        wk2a[4] = g * k1.x; wk2a[5] = g * k1.y; wk2a[6] = g * k1.z; wk2a[7] = g * k1.w;
    }
    if (tid < 8) sRed[tid >> 2][tid & 3] = 0.f;   // zero both buffers
    __syncthreads();

    const unsigned long long* gm = g_masks + (long)b * NSTEPS;

    for (int t = 0; t < NSTEPS; ++t) {
        const float* rp = sRed[(t + 1) & 1];
        const float apl = fmaxf(rp[0] + rp[1] + rp[2] + rp[3], 0.f);

#pragma unroll
        for (int j = 0; j < KPER; ++j) vd[j] = ALPHA * vd[j] - apl * wa2k[j];

        unsigned long long m = gm[t];   // wave-uniform scalar load
        while (m) {
            const int p0 = __builtin_ctzll(m); m &= m - 1;
            int p1 = p0; float f1 = 0.f;
            if (m) { p1 = __builtin_ctzll(m); m &= m - 1; f1 = 1.f; }
            if (act) {
                const float4* w0 = (const float4*)(pn_to_kc + (long)p0 * NKC + kbase);
                const float4* w1 = (const float4*)(pn_to_kc + (long)p1 * NKC + kbase);
                float4 a0 = w0[0], a1 = w0[1];
                float4 b0 = w1[0], b1 = w1[1];
                vd[0] += a0.x; vd[1] += a0.y; vd[2] += a0.z; vd[3] += a0.w;
                vd[4] += a1.x; vd[5] += a1.y; vd[6] += a1.z; vd[7] += a1.w;
                vd[0] += f1 * b0.x; vd[1] += f1 * b0.y; vd[2] += f1 * b0.z; vd[3] += f1 * b0.w;
                vd[4] += f1 * b1.x; vd[5] += f1 * b1.y; vd[6] += f1 * b1.z; vd[7] += f1 * b1.w;
            }
        }

        float aplp = 0.f;
#pragma unroll
        for (int j = 0; j < KPER; ++j) {
            va[j] = ALPHA * va[j] + GSOMA * (vd[j] - va[j]);
            float s = (va[j] - VTH) > 0.f ? 1.f : 0.f;
            va[j] *= (1.f - s);
            cnt[j] += s;
            aplp += s * wk2a[j];
        }
        for (int off = 32; off > 0; off >>= 1) aplp += __shfl_xor(aplp, off, 64);
        if (lane == 0) sRed[t & 1][wid] = aplp;
        __syncthreads();
    }

    float acc[NOD];
#pragma unroll
    for (int o = 0; o < NOD; ++o) acc[o] = 0.f;
    if (act) {
#pragma unroll
        for (int j = 0; j < KPER; ++j) {
            float r = cnt[j] / 20.0f;
            if (r != 0.f) {
                const float* wr = dec_w + (long)(kbase + j) * NOD;
#pragma unroll
                for (int o = 0; o < NOD; ++o) acc[o] += r * wr[o];
            }
        }
    }
#pragma unroll
    for (int o = 0; o < NOD; ++o) {
        float v = acc[o];
        for (int off = 32; off > 0; off >>= 1) v += __shfl_xor(v, off, 64);
        if (lane == 0) sRed2[wid * NOD + o] = v;
    }
    __syncthreads();
    if (tid < NOD) {
        float v = sRed2[tid] + sRed2[NOD + tid] + sRed2[2 * NOD + tid] +
                  sRed2[3 * NOD + tid] + dec_b[tid];
        out[(long)b * NOD + tid] = v;
    }
}

// ===================== Fallback: round-1 fused kernel (proven) =====================
__global__ __launch_bounds__(TPB)
void snn_fused(const float* __restrict__ or_input, const float* __restrict__ or_gains,
               const float* __restrict__ mapping, const float* __restrict__ orn_to_pn,
               const float* __restrict__ orn_to_ln, const float* __restrict__ ln_to_pn,
               const float* __restrict__ pn_to_kc, const float* __restrict__ kc_to_apl,
               const float* __restrict__ apl_to_kc, const float* __restrict__ dec_w,
               const float* __restrict__ dec_b, float* __restrict__ out)
{
    __shared__ float sW_ol[NORN * NLN];
    __shared__ float sW_op[NORN * NPN];
    __shared__ float sW_lp[NLN * NPN];
    __shared__ float sDrive[NORN];
    __shared__ float sSpg[NOR];
    __shared__ float sOrn[NORN];
    __shared__ float sLn[NLN];
    __shared__ float sApl;
    __shared__ float sRed[4];
    __shared__ float sRed2[4 * NOD];
    __shared__ unsigned long long sMask;

    const int tid = threadIdx.x;
    const int b   = blockIdx.x;

    for (int i = tid; i < NORN * NLN; i += TPB) sW_ol[i] = orn_to_ln[i];
    for (int i = tid; i < NORN * NPN; i += TPB) sW_op[i] = orn_to_pn[i];
    for (int i = tid; i < NLN * NPN;  i += TPB) sW_lp[i] = ln_to_pn[i];
    if (tid < NOR) sSpg[tid] = log1pf(expf(or_gains[tid]));
    if (tid == 0)  sApl = 0.f;
    __syncthreads();

    if (tid < NORN) {
        const float* x = or_input + (long)b * NOR;
        float d = 0.f;
        for (int i = 0; i < NOR; ++i) d += x[i] * sSpg[i] * mapping[i * NORN + tid];
        sDrive[tid] = d * ISCALE;
    }

    const int  kbase = tid * KPER;
    const bool act   = (kbase < NKC);
    float vd[KPER], va[KPER], cnt[KPER], wa2k[KPER], wk2a[KPER];
#pragma unroll
    for (int j = 0; j < KPER; ++j) {
        vd[j] = 0.f; va[j] = 0.f; cnt[j] = 0.f;
        wa2k[j] = act ? apl_to_kc[kbase + j] : 0.f;
        wk2a[j] = act ? kc_to_apl[kbase + j] : 0.f;
    }
    float v_orn = 0.f, v_ln = 0.f, v_pn = 0.f, v_pn_exc = 0.f;
    __syncthreads();

    for (int t = 0; t < NSTEPS; ++t) {
        if (tid < NORN) {
            v_orn = ALPHA * v_orn + sDrive[tid];
            float s = (v_orn - VTH) > 0.f ? 1.f : 0.f;
            v_orn *= (1.f - s);
            sOrn[tid] = s;
        }
        __syncthreads();
        if (tid < NLN) {
            float a = 0.f;
            for (int o = 0; o < NORN; ++o) a += sOrn[o] * sW_ol[o * NLN + tid];
            v_ln = ALPHA * v_ln + a;
            float s = (v_ln - VTH) > 0.f ? 1.f : 0.f;
            v_ln *= (1.f - s);
            sLn[tid] = s;
        } else if (tid >= 64 && tid < 64 + NPN) {
            const int j = tid - 64;
            float a = 0.f;
            for (int o = 0; o < NORN; ++o) a += sOrn[o] * sW_op[o * NPN + j];
            v_pn_exc = a;
        }
        __syncthreads();
        if (tid >= 64 && tid < 64 + NPN) {
            const int j = tid - 64;
            float inh = 0.f;
            for (int l = 0; l < NLN; ++l) inh += sLn[l] * sW_lp[l * NPN + j];
            v_pn = ALPHA * v_pn + v_pn_exc - inh;
            bool s = (v_pn - VTH) > 0.f;
            if (s) v_pn = 0.f;
            unsigned long long bal = __ballot(s);
            if (tid == 64) sMask = bal;
        }
        __syncthreads();
        {
            const float apl = sApl;
#pragma unroll
            for (int j = 0; j < KPER; ++j) vd[j] = ALPHA * vd[j] - apl * wa2k[j];
            unsigned long long m = sMask;
            while (m) {
                const int p = __builtin_ctzll(m);
                m &= m - 1;
                if (act) {
                    const float4* w = (const float4*)(pn_to_kc + (long)p * NKC + kbase);
                    float4 w0 = w[0], w1 = w[1];
                    vd[0] += w0.x; vd[1] += w0.y; vd[2] += w0.z; vd[3] += w0.w;
                    vd[4] += w1.x; vd[5] += w1.y; vd[6] += w1.z; vd[7] += w1.w;
                }
            }
            float aplp = 0.f;
#pragma unroll
            for (int j = 0; j < KPER; ++j) {
                va[j] = ALPHA * va[j] + GSOMA * (vd[j] - va[j]);
                float s = (va[j] - VTH) > 0.f ? 1.f : 0.f;
                va[j] *= (1.f - s);
                cnt[j] += s;
                aplp += s * wk2a[j];
            }
            for (int off = 32; off > 0; off >>= 1) aplp += __shfl_xor(aplp, off, 64);
            if ((tid & 63) == 0) sRed[tid >> 6] = aplp;
        }
        __syncthreads();
        if (tid == 0) {
            float a = sRed[0] + sRed[1] + sRed[2] + sRed[3];
            sApl = fmaxf(a, 0.f);
        }
    }

    float acc[NOD];
#pragma unroll
    for (int o = 0; o < NOD; ++o) acc[o] = 0.f;
    if (act) {
#pragma unroll
        for (int j = 0; j < KPER; ++j) {
            float r = cnt[j] / 20.0f;
            if (r != 0.f) {
                const float* wr = dec_w + (long)(kbase + j) * NOD;
#pragma unroll
                for (int o = 0; o < NOD; ++o) acc[o] += r * wr[o];
            }
        }
    }
#pragma unroll
    for (int o = 0; o < NOD; ++o) {
        float v = acc[o];
        for (int off = 32; off > 0; off >>= 1) v += __shfl_xor(v, off, 64);
        if ((tid & 63) == 0) sRed2[(tid >> 6) * NOD + o] = v;
    }
    __syncthreads();
    if (tid < NOD) {
        float v = sRed2[tid] + sRed2[NOD + tid] + sRed2[2 * NOD + tid] +
                  sRed2[3 * NOD + tid] + dec_b[tid];
        out[(long)b * NOD + tid] = v;
    }
}

extern "C" void kernel_launch(void* const* d_in, const int* in_sizes, int n_in,
                              void* d_out, int out_size, void* d_ws, size_t ws_size,
                              hipStream_t stream) {
    (void)n_in; (void)out_size;
    const float* or_input  = (const float*)d_in[0];
    const float* or_gains  = (const float*)d_in[1];
    const float* mapping   = (const float*)d_in[2];
    const float* orn_to_pn = (const float*)d_in[3];
    const float* orn_to_ln = (const float*)d_in[4];
    const float* ln_to_pn  = (const float*)d_in[5];
    const float* pn_to_kc  = (const float*)d_in[6];
    const float* kc_to_apl = (const float*)d_in[7];
    const float* apl_to_kc = (const float*)d_in[8];
    const float* dec_w     = (const float*)d_in[9];
    const float* dec_b     = (const float*)d_in[10];
    float* out = (float*)d_out;

    const int batch = in_sizes[0] / NOR;  // 4096
    const size_t needPN = (size_t)batch * NSTEPS * sizeof(unsigned long long);  // 0.66 MB

    if (ws_size >= needPN) {
        unsigned long long* gPN = (unsigned long long*)d_ws;
        hipLaunchKernelGGL(phase1_fused, dim3((batch + 1) / 2), dim3(64), 0, stream,
                           or_input, or_gains, mapping, orn_to_ln, orn_to_pn, ln_to_pn,
                           gPN, batch);
        hipLaunchKernelGGL(phase2_kernel, dim3(batch), dim3(TPB), 0, stream,
                           gPN, pn_to_kc, kc_to_apl, apl_to_kc, dec_w, dec_b, out);
    } else {
        hipLaunchKernelGGL(snn_fused, dim3(batch), dim3(TPB), 0, stream,
                           or_input, or_gains, mapping, orn_to_pn, orn_to_ln,
                           ln_to_pn, pn_to_kc, kc_to_apl, apl_to_kc, dec_w, dec_b, out);
    }
}

// Round 3
// 224.088 us; speedup vs baseline: 1.0203x; 1.0203x over previous
//
#include <hip/hip_runtime.h>

#define NSTEPS 20
#define ALPHA  0.9f
#define VTH    1.0f
#define GSOMA  0.3f
#define ISCALE 0.5f

#define NOR  21
#define NORN 42
#define NLN  56
#define NPN  42
#define NKC  2000
#define NOD  34

#define TPB  256
#define KPER 8   // KCs per consumer thread: 250 * 8 = 2000

// ============ Phase 1 (sparse-LDS): ORN + LN + PN dynamics -> PN spike masks ============
// 256-thread blocks = 4 independent rows (1 wave each). All three weight matrices
// staged once into LDS (25.9 KB); masked accumulates iterate ONLY set mask bits via
// uniform ctz loops (SALU loop control, 3 issue-ops per spike term) instead of dense
// bit-extract (3-4 VALU per term over all 42/56 terms). VGPR stays ~50 (no weight
// arrays in registers). No barriers in the time loop (waves independent).
// Exactness: ascending-index skip-zero accumulation is bitwise identical to the
// proven dense +0.0 accumulation (weights >= 0, fp32 x+0.0f == x); LIF update
// expressions copied verbatim from the proven phase1a/phase1b kernels.
__global__ __launch_bounds__(TPB)
void phase1_sparse(const float* __restrict__ or_input,   // [B,21]
                   const float* __restrict__ or_gains,   // [21]
                   const float* __restrict__ mapping,    // [21,42]
                   const float* __restrict__ orn_to_ln,  // [42,56]
                   const float* __restrict__ orn_to_pn,  // [42,42]
                   const float* __restrict__ ln_to_pn,   // [56,42]
                   unsigned long long* __restrict__ gPN, // [B,20]
                   int batch)
{
    __shared__ float sOl[NORN * NLN];   // 2352
    __shared__ float sOp[NORN * NPN];   // 1764
    __shared__ float sLp[NLN * NPN];    // 2352

    const int tid = threadIdx.x;
    for (int i = tid; i < NORN * NLN; i += TPB) sOl[i] = orn_to_ln[i];
    for (int i = tid; i < NORN * NPN; i += TPB) sOp[i] = orn_to_pn[i];
    for (int i = tid; i < NLN * NPN;  i += TPB) sLp[i] = ln_to_pn[i];
    __syncthreads();

    const int lane = tid & 63;
    const int wid  = tid >> 6;
    const int row  = blockIdx.x * 4 + wid;
    if (row >= batch) return;   // whole wave exits together; no barriers below

    // ---- per-row graded ORN drive (verbatim from proven phase1a) ----
    float spg = 0.f;
    if (lane < NOR) spg = log1pf(expf(or_gains[lane]));  // softplus

    float drive = 0.f;
    {
        const float* x = or_input + (long)row * NOR;
        const int jo = lane < NORN ? lane : 0;
#pragma unroll
        for (int i = 0; i < NOR; ++i) {
            float g = __shfl(spg, i);
            drive += x[i] * g * mapping[i * NORN + jo];
        }
        drive *= ISCALE;
    }

    const int jl = lane < NLN ? lane : 0;
    const int jp = lane < NPN ? lane : 0;

    float v_orn = 0.f, v_ln = 0.f, v_pn = 0.f;
    unsigned long long* outm = gPN + (long)row * NSTEPS;

    for (int t = 0; t < NSTEPS; ++t) {
        // ---- ORN LIF (lane = ORN index) ----
        bool so = false;
        if (lane < NORN) {
            v_orn = ALPHA * v_orn + drive;
            so = (v_orn - VTH) > 0.f;
            if (so) v_orn = 0.f;
        }
        unsigned long long mO = __ballot(so);

        // ---- LN input + PN excitation: one sparse pass over ORN spikes ----
        // ascending-p ctz order == ascending dense order (skip-zero, exact)
        float aln = 0.f, apn = 0.f;
        {
            unsigned long long m = mO;
            while (m) {
                const int p = __builtin_ctzll(m);
                m &= m - 1;
                aln += sOl[p * NLN + jl];
                apn += sOp[p * NPN + jp];
            }
        }

        bool sl = false;
        if (lane < NLN) {
            v_ln = ALPHA * v_ln + aln;
            sl = (v_ln - VTH) > 0.f;
            if (sl) v_ln = 0.f;
        }
        unsigned long long mL = __ballot(sl);

        // ---- PN inhibition: sparse pass over LN spikes ----
        float h = 0.f;
        {
            unsigned long long m = mL;
            while (m) {
                const int l = __builtin_ctzll(m);
                m &= m - 1;
                h += sLp[l * NPN + jp];
            }
        }

        bool sp = false;
        if (lane < NPN) {
            v_pn = ALPHA * v_pn + apn - h;
            sp = (v_pn - VTH) > 0.f;
            if (sp) v_pn = 0.f;
        }
        const unsigned long long mP = __ballot(sp);
        if (lane == 0) outm[t] = mP;
    }
}

// ===================== Phase 2: KC two-compartment + APL + logits =====================
// (R5/R9/R13-proven 93-95 us / absmax 0.0 — unchanged)
__global__ __launch_bounds__(TPB)
void phase2_kernel(const unsigned long long* __restrict__ g_masks, // [B,20]
                   const float* __restrict__ pn_to_kc,  // [42,2000]
                   const float* __restrict__ kc_to_apl, // [2000,1]
                   const float* __restrict__ apl_to_kc, // [1,2000]
                   const float* __restrict__ dec_w,     // [2000,34]
                   const float* __restrict__ dec_b,     // [34]
                   float* __restrict__ out)             // [B,34]
{
    __shared__ float sRed[2][4];
    __shared__ float sRed2[4 * NOD];

    const int tid  = threadIdx.x;
    const int lane = tid & 63;
    const int wid  = tid >> 6;
    const int b    = blockIdx.x;

    const int  kbase = tid * KPER;
    const bool act   = (kbase < NKC);   // tid < 250
    float vd[KPER], va[KPER], cnt[KPER], wa2k[KPER], wk2a[KPER];
#pragma unroll
    for (int j = 0; j < KPER; ++j) { vd[j] = 0.f; va[j] = 0.f; cnt[j] = 0.f; }
    {
        const float4* a4 = (const float4*)(apl_to_kc + (act ? kbase : 0));
        const float4* k4 = (const float4*)(kc_to_apl + (act ? kbase : 0));
        float4 a0 = a4[0], a1 = a4[1], k0 = k4[0], k1 = k4[1];
        const float g = act ? 1.f : 0.f;
        wa2k[0] = g * a0.x; wa2k[1] = g * a0.y; wa2k[2] = g * a0.z; wa2k[3] = g * a0.w;
        wa2k[4] = g * a1.x; wa2k[5] = g * a1.y; wa2k[6] = g * a1.z; wa2k[7] = g * a1.w;
        wk2a[0] = g * k0.x; wk2a[1] = g * k0.y; wk2a[2] = g * k0.z; wk2a[3] = g * k0.w;
        wk2a[4] = g * k1.x; wk2a[5] = g * k1.y; wk2a[6] = g * k1.z; wk2a[7] = g * k1.w;
    }
    if (tid < 8) sRed[tid >> 2][tid & 3] = 0.f;   // zero both buffers
    __syncthreads();

    const unsigned long long* gm = g_masks + (long)b * NSTEPS;

    for (int t = 0; t < NSTEPS; ++t) {
        const float* rp = sRed[(t + 1) & 1];
        const float apl = fmaxf(rp[0] + rp[1] + rp[2] + rp[3], 0.f);

#pragma unroll
        for (int j = 0; j < KPER; ++j) vd[j] = ALPHA * vd[j] - apl * wa2k[j];

        unsigned long long m = gm[t];   // wave-uniform scalar load
        while (m) {
            const int p0 = __builtin_ctzll(m); m &= m - 1;
            int p1 = p0; float f1 = 0.f;
            if (m) { p1 = __builtin_ctzll(m); m &= m - 1; f1 = 1.f; }
            if (act) {
                const float4* w0 = (const float4*)(pn_to_kc + (long)p0 * NKC + kbase);
                const float4* w1 = (const float4*)(pn_to_kc + (long)p1 * NKC + kbase);
                float4 a0 = w0[0], a1 = w0[1];
                float4 b0 = w1[0], b1 = w1[1];
                vd[0] += a0.x; vd[1] += a0.y; vd[2] += a0.z; vd[3] += a0.w;
                vd[4] += a1.x; vd[5] += a1.y; vd[6] += a1.z; vd[7] += a1.w;
                vd[0] += f1 * b0.x; vd[1] += f1 * b0.y; vd[2] += f1 * b0.z; vd[3] += f1 * b0.w;
                vd[4] += f1 * b1.x; vd[5] += f1 * b1.y; vd[6] += f1 * b1.z; vd[7] += f1 * b1.w;
            }
        }

        float aplp = 0.f;
#pragma unroll
        for (int j = 0; j < KPER; ++j) {
            va[j] = ALPHA * va[j] + GSOMA * (vd[j] - va[j]);
            float s = (va[j] - VTH) > 0.f ? 1.f : 0.f;
            va[j] *= (1.f - s);
            cnt[j] += s;
            aplp += s * wk2a[j];
        }
        for (int off = 32; off > 0; off >>= 1) aplp += __shfl_xor(aplp, off, 64);
        if (lane == 0) sRed[t & 1][wid] = aplp;
        __syncthreads();
    }

    float acc[NOD];
#pragma unroll
    for (int o = 0; o < NOD; ++o) acc[o] = 0.f;
    if (act) {
#pragma unroll
        for (int j = 0; j < KPER; ++j) {
            float r = cnt[j] / 20.0f;
            if (r != 0.f) {
                const float* wr = dec_w + (long)(kbase + j) * NOD;
#pragma unroll
                for (int o = 0; o < NOD; ++o) acc[o] += r * wr[o];
            }
        }
    }
#pragma unroll
    for (int o = 0; o < NOD; ++o) {
        float v = acc[o];
        for (int off = 32; off > 0; off >>= 1) v += __shfl_xor(v, off, 64);
        if (lane == 0) sRed2[wid * NOD + o] = v;
    }
    __syncthreads();
    if (tid < NOD) {
        float v = sRed2[tid] + sRed2[NOD + tid] + sRed2[2 * NOD + tid] +
                  sRed2[3 * NOD + tid] + dec_b[tid];
        out[(long)b * NOD + tid] = v;
    }
}

// ===================== Fallback: round-1 fused kernel (proven) =====================
__global__ __launch_bounds__(TPB)
void snn_fused(const float* __restrict__ or_input, const float* __restrict__ or_gains,
               const float* __restrict__ mapping, const float* __restrict__ orn_to_pn,
               const float* __restrict__ orn_to_ln, const float* __restrict__ ln_to_pn,
               const float* __restrict__ pn_to_kc, const float* __restrict__ kc_to_apl,
               const float* __restrict__ apl_to_kc, const float* __restrict__ dec_w,
               const float* __restrict__ dec_b, float* __restrict__ out)
{
    __shared__ float sW_ol[NORN * NLN];
    __shared__ float sW_op[NORN * NPN];
    __shared__ float sW_lp[NLN * NPN];
    __shared__ float sDrive[NORN];
    __shared__ float sSpg[NOR];
    __shared__ float sOrn[NORN];
    __shared__ float sLn[NLN];
    __shared__ float sApl;
    __shared__ float sRed[4];
    __shared__ float sRed2[4 * NOD];
    __shared__ unsigned long long sMask;

    const int tid = threadIdx.x;
    const int b   = blockIdx.x;

    for (int i = tid; i < NORN * NLN; i += TPB) sW_ol[i] = orn_to_ln[i];
    for (int i = tid; i < NORN * NPN; i += TPB) sW_op[i] = orn_to_pn[i];
    for (int i = tid; i < NLN * NPN;  i += TPB) sW_lp[i] = ln_to_pn[i];
    if (tid < NOR) sSpg[tid] = log1pf(expf(or_gains[tid]));
    if (tid == 0)  sApl = 0.f;
    __syncthreads();

    if (tid < NORN) {
        const float* x = or_input + (long)b * NOR;
        float d = 0.f;
        for (int i = 0; i < NOR; ++i) d += x[i] * sSpg[i] * mapping[i * NORN + tid];
        sDrive[tid] = d * ISCALE;
    }

    const int  kbase = tid * KPER;
    const bool act   = (kbase < NKC);
    float vd[KPER], va[KPER], cnt[KPER], wa2k[KPER], wk2a[KPER];
#pragma unroll
    for (int j = 0; j < KPER; ++j) {
        vd[j] = 0.f; va[j] = 0.f; cnt[j] = 0.f;
        wa2k[j] = act ? apl_to_kc[kbase + j] : 0.f;
        wk2a[j] = act ? kc_to_apl[kbase + j] : 0.f;
    }
    float v_orn = 0.f, v_ln = 0.f, v_pn = 0.f, v_pn_exc = 0.f;
    __syncthreads();

    for (int t = 0; t < NSTEPS; ++t) {
        if (tid < NORN) {
            v_orn = ALPHA * v_orn + sDrive[tid];
            float s = (v_orn - VTH) > 0.f ? 1.f : 0.f;
            v_orn *= (1.f - s);
            sOrn[tid] = s;
        }
        __syncthreads();
        if (tid < NLN) {
            float a = 0.f;
            for (int o = 0; o < NORN; ++o) a += sOrn[o] * sW_ol[o * NLN + tid];
            v_ln = ALPHA * v_ln + a;
            float s = (v_ln - VTH) > 0.f ? 1.f : 0.f;
            v_ln *= (1.f - s);
            sLn[tid] = s;
        } else if (tid >= 64 && tid < 64 + NPN) {
            const int j = tid - 64;
            float a = 0.f;
            for (int o = 0; o < NORN; ++o) a += sOrn[o] * sW_op[o * NPN + j];
            v_pn_exc = a;
        }
        __syncthreads();
        if (tid >= 64 && tid < 64 + NPN) {
            const int j = tid - 64;
            float inh = 0.f;
            for (int l = 0; l < NLN; ++l) inh += sLn[l] * sW_lp[l * NPN + j];
            v_pn = ALPHA * v_pn + v_pn_exc - inh;
            bool s = (v_pn - VTH) > 0.f;
            if (s) v_pn = 0.f;
            unsigned long long bal = __ballot(s);
            if (tid == 64) sMask = bal;
        }
        __syncthreads();
        {
            const float apl = sApl;
#pragma unroll
            for (int j = 0; j < KPER; ++j) vd[j] = ALPHA * vd[j] - apl * wa2k[j];
            unsigned long long m = sMask;
            while (m) {
                const int p = __builtin_ctzll(m);
                m &= m - 1;
                if (act) {
                    const float4* w = (const float4*)(pn_to_kc + (long)p * NKC + kbase);
                    float4 w0 = w[0], w1 = w[1];
                    vd[0] += w0.x; vd[1] += w0.y; vd[2] += w0.z; vd[3] += w0.w;
                    vd[4] += w1.x; vd[5] += w1.y; vd[6] += w1.z; vd[7] += w1.w;
                }
            }
            float aplp = 0.f;
#pragma unroll
            for (int j = 0; j < KPER; ++j) {
                va[j] = ALPHA * va[j] + GSOMA * (vd[j] - va[j]);
                float s = (va[j] - VTH) > 0.f ? 1.f : 0.f;
                va[j] *= (1.f - s);
                cnt[j] += s;
                aplp += s * wk2a[j];
            }
            for (int off = 32; off > 0; off >>= 1) aplp += __shfl_xor(aplp, off, 64);
            if ((tid & 63) == 0) sRed[tid >> 6] = aplp;
        }
        __syncthreads();
        if (tid == 0) {
            float a = sRed[0] + sRed[1] + sRed[2] + sRed[3];
            sApl = fmaxf(a, 0.f);
        }
    }

    float acc[NOD];
#pragma unroll
    for (int o = 0; o < NOD; ++o) acc[o] = 0.f;
    if (act) {
#pragma unroll
        for (int j = 0; j < KPER; ++j) {
            float r = cnt[j] / 20.0f;
            if (r != 0.f) {
                const float* wr = dec_w + (long)(kbase + j) * NOD;
#pragma unroll
                for (int o = 0; o < NOD; ++o) acc[o] += r * wr[o];
            }
        }
    }
#pragma unroll
    for (int o = 0; o < NOD; ++o) {
        float v = acc[o];
        for (int off = 32; off > 0; off >>= 1) v += __shfl_xor(v, off, 64);
        if ((tid & 63) == 0) sRed2[(tid >> 6) * NOD + o] = v;
    }
    __syncthreads();
    if (tid < NOD) {
        float v = sRed2[tid] + sRed2[NOD + tid] + sRed2[2 * NOD + tid] +
                  sRed2[3 * NOD + tid] + dec_b[tid];
        out[(long)b * NOD + tid] = v;
    }
}

extern "C" void kernel_launch(void* const* d_in, const int* in_sizes, int n_in,
                              void* d_out, int out_size, void* d_ws, size_t ws_size,
                              hipStream_t stream) {
    (void)n_in; (void)out_size;
    const float* or_input  = (const float*)d_in[0];
    const float* or_gains  = (const float*)d_in[1];
    const float* mapping   = (const float*)d_in[2];
    const float* orn_to_pn = (const float*)d_in[3];
    const float* orn_to_ln = (const float*)d_in[4];
    const float* ln_to_pn  = (const float*)d_in[5];
    const float* pn_to_kc  = (const float*)d_in[6];
    const float* kc_to_apl = (const float*)d_in[7];
    const float* apl_to_kc = (const float*)d_in[8];
    const float* dec_w     = (const float*)d_in[9];
    const float* dec_b     = (const float*)d_in[10];
    float* out = (float*)d_out;

    const int batch = in_sizes[0] / NOR;  // 4096
    const size_t needPN = (size_t)batch * NSTEPS * sizeof(unsigned long long);  // 0.66 MB

    if (ws_size >= needPN) {
        unsigned long long* gPN = (unsigned long long*)d_ws;
        hipLaunchKernelGGL(phase1_sparse, dim3((batch + 3) / 4), dim3(TPB), 0, stream,
                           or_input, or_gains, mapping, orn_to_ln, orn_to_pn, ln_to_pn,
                           gPN, batch);
        hipLaunchKernelGGL(phase2_kernel, dim3(batch), dim3(TPB), 0, stream,
                           gPN, pn_to_kc, kc_to_apl, apl_to_kc, dec_w, dec_b, out);
    } else {
        hipLaunchKernelGGL(snn_fused, dim3(batch), dim3(TPB), 0, stream,
                           or_input, or_gains, mapping, orn_to_pn, orn_to_ln,
                           ln_to_pn, pn_to_kc, kc_to_apl, apl_to_kc, dec_w, dec_b, out);
    }
}